// Round 1
// baseline (284.384 us; speedup 1.0000x reference)
//
#include <hip/hip_runtime.h>
#include <math.h>

#define LOG2E 1.44269504088896340736f
#define CHUNK_MAX 512   // max j-chunk per block (LDS: 512 float2 = 4 KB)

// Zero the accumulator surface (harness poisons d_out with 0xAA each call).
__global__ void zero_out_kernel(float* __restrict__ out, int n) {
    int i = blockIdx.x * blockDim.x + threadIdx.x;
    if (i < n) out[i] = 0.0f;
}

// One wave per block. lane -> output row i (64 rows per block.x).
// blockIdx.y -> uniform j-chunk, so c-row loads are wave-uniform (s_load path).
// Accumulates  sum_j beta_j * exp2( log2e*dot(x_i,c_j) + a_i + s_j )
// where a_i = -0.5*log2e*|x_i|^2, s_j = -0.5*log2e*|c_j|^2, via fp32 atomicAdd.
__global__ __launch_bounds__(64, 4) void krr_partial_kernel(
    const float* __restrict__ x,
    const float* __restrict__ c,
    const float* __restrict__ beta,
    float* __restrict__ out,
    int N, int M, int chunk)
{
    __shared__ float2 sw[CHUNK_MAX];   // {s_j, beta_j} for this chunk

    const int lane = threadIdx.x;      // 0..63
    const int j0 = blockIdx.y * chunk;
    const int j1 = min(M, j0 + chunk);

    // ---- prep: per-j scalars for this chunk into LDS ----
    for (int j = j0 + lane; j < j1; j += 64) {
        const float4* cr = (const float4*)(c + (size_t)j * 32);
        float s = 0.0f;
#pragma unroll
        for (int q = 0; q < 8; ++q) {
            float4 v = cr[q];
            s = fmaf(v.x, v.x, s); s = fmaf(v.y, v.y, s);
            s = fmaf(v.z, v.z, s); s = fmaf(v.w, v.w, s);
        }
        sw[j - j0] = make_float2(-0.5f * LOG2E * s, beta[j]);
    }
    __syncthreads();

    // ---- load this lane's x row, pre-scaled by log2e ----
    const int i = blockIdx.x * 64 + lane;
    const bool valid = (i < N);
    const float4* xrow = (const float4*)(x + (size_t)(valid ? i : 0) * 32);

    float xr[32];
    float xsq = 0.0f;
#pragma unroll
    for (int q = 0; q < 8; ++q) {
        float4 v = xrow[q];
        xsq = fmaf(v.x, v.x, xsq); xsq = fmaf(v.y, v.y, xsq);
        xsq = fmaf(v.z, v.z, xsq); xsq = fmaf(v.w, v.w, xsq);
        xr[4*q+0] = v.x * LOG2E;  xr[4*q+1] = v.y * LOG2E;
        xr[4*q+2] = v.z * LOG2E;  xr[4*q+3] = v.w * LOG2E;
    }
    const float ai = -0.5f * LOG2E * xsq;

    // ---- hot loop: 32 v_fmac + 1 v_exp + 2 ops per j ----
    float acc = 0.0f;
#pragma unroll 2
    for (int j = j0; j < j1; ++j) {
        const float4* cr = (const float4*)(c + (size_t)j * 32);  // wave-uniform addr
        const float2 s2 = sw[j - j0];                            // LDS broadcast
        float d = ai + s2.x;
#pragma unroll
        for (int q = 0; q < 8; ++q) {
            float4 v = cr[q];
            d = fmaf(xr[4*q+0], v.x, d);
            d = fmaf(xr[4*q+1], v.y, d);
            d = fmaf(xr[4*q+2], v.z, d);
            d = fmaf(xr[4*q+3], v.w, d);
        }
        acc = fmaf(s2.y, exp2f(d), acc);   // exp2f -> v_exp_f32
    }

    if (valid) atomicAdd(out + i, acc);
}

// out[i] = softplus(out[i])
__global__ void softplus_kernel(float* __restrict__ out, int n) {
    int i = blockIdx.x * blockDim.x + threadIdx.x;
    if (i < n) {
        float t = out[i];
        out[i] = (t > 20.0f) ? t : log1pf(expf(t));
    }
}

extern "C" void kernel_launch(void* const* d_in, const int* in_sizes, int n_in,
                              void* d_out, int out_size, void* d_ws, size_t ws_size,
                              hipStream_t stream) {
    const float* x    = (const float*)d_in[0];   // (N, 32)
    const float* c    = (const float*)d_in[1];   // (M, 32)
    const float* beta = (const float*)d_in[2];   // (M,)
    float* out = (float*)d_out;                  // (N,)

    const int N = out_size;          // 40000
    const int M = in_sizes[2];       // 4000

    // j-splits: at least 8 (load balance), chunk must fit CHUNK_MAX
    int jc = (M + CHUNK_MAX - 1) / CHUNK_MAX;
    if (jc < 8) jc = 8;
    int chunk = (M + jc - 1) / jc;   // 500 for M=4000

    zero_out_kernel<<<dim3((N + 255) / 256), dim3(256), 0, stream>>>(out, N);

    dim3 grid((N + 63) / 64, jc);
    krr_partial_kernel<<<grid, dim3(64), 0, stream>>>(x, c, beta, out, N, M, chunk);

    softplus_kernel<<<dim3((N + 255) / 256), dim3(256), 0, stream>>>(out, N);
}

// Round 2
// 167.840 us; speedup vs baseline: 1.6944x; 1.6944x over previous
//
#include <hip/hip_runtime.h>
#include <math.h>

#define LOG2E 1.44269504088896340736f

typedef _Float16 f16x8 __attribute__((ext_vector_type(8)));
typedef float f32x4 __attribute__((ext_vector_type(4)));

// ---------------- zero / softplus passes ----------------
__global__ void zero_out_kernel(float* __restrict__ out, int n) {
    int i = blockIdx.x * blockDim.x + threadIdx.x;
    if (i < n) out[i] = 0.0f;
}

__global__ void softplus_kernel(float* __restrict__ out, int n) {
    int i = blockIdx.x * blockDim.x + threadIdx.x;
    if (i < n) {
        float t = out[i];
        out[i] = (t > 20.0f) ? t : log1pf(expf(t));
    }
}

// ---------------- pass 1: convert c -> f16 hi/lo, per-j scalars ----------------
// chi/clo: (M16 x 32) halves; sb[j] = { -0.5*log2e*|c_j|^2, beta_j }, zero-padded.
__global__ void prep_c_kernel(const float* __restrict__ c,
                              const float* __restrict__ beta,
                              _Float16* __restrict__ chi,
                              _Float16* __restrict__ clo,
                              float2* __restrict__ sb,
                              int M, int M16) {
    int j = blockIdx.x * blockDim.x + threadIdx.x;
    if (j >= M16) return;
    if (j < M) {
        const float4* cr = (const float4*)(c + (size_t)j * 32);
        float s = 0.0f;
#pragma unroll
        for (int q = 0; q < 8; ++q) {
            float4 v = cr[q];
            s = fmaf(v.x, v.x, s); s = fmaf(v.y, v.y, s);
            s = fmaf(v.z, v.z, s); s = fmaf(v.w, v.w, s);
            float vv[4] = {v.x, v.y, v.z, v.w};
#pragma unroll
            for (int t = 0; t < 4; ++t) {
                float f = vv[t];
                _Float16 h = (_Float16)f;
                chi[(size_t)j * 32 + q * 4 + t] = h;
                clo[(size_t)j * 32 + q * 4 + t] = (_Float16)(f - (float)h);
            }
        }
        sb[j] = make_float2(-0.5f * LOG2E * s, beta[j]);
    } else {
#pragma unroll
        for (int t = 0; t < 32; ++t) {
            chi[(size_t)j * 32 + t] = (_Float16)0.0f;
            clo[(size_t)j * 32 + t] = (_Float16)0.0f;
        }
        sb[j] = make_float2(0.0f, 0.0f);
    }
}

// ---------------- main: fused MFMA RBF matvec ----------------
// Block = 4 waves; wave w handles i-tile (blockIdx.x*4 + w) = 16 rows.
// blockIdx.y selects a chunk of 16-col j-tiles. Per j-tile:
//   cross = x_hi*c_hi + x_lo*c_hi + x_hi*c_lo   (x pre-scaled by log2e)
//   out_i += beta_j * exp2(cross + a_i + s_j)
// C layout (verified m89): col = lane&15, row = (lane>>4)*4 + reg.
// A/B fragment: elem k = (lane>>4)*8 + t for row/col (lane&15).
__global__ __launch_bounds__(256) void krr_mfma_kernel(
    const float* __restrict__ x,
    const _Float16* __restrict__ chi,
    const _Float16* __restrict__ clo,
    const float2* __restrict__ sb,
    float* __restrict__ out,
    int N, int JT, int jt_per)
{
    __shared__ float ai_lds[4][16];
    const int wave = threadIdx.x >> 6;
    const int lane = threadIdx.x & 63;
    const int m    = lane & 15;
    const int quad = lane >> 4;
    const int kbase = quad * 8;

    const int itile = blockIdx.x * 4 + wave;
    const int i = itile * 16 + m;
    const int iclamped = (i < N) ? i : (N - 1);

    // ---- load this wave's 16 x-rows as A fragments (done once) ----
    const float4* xp = (const float4*)(x + (size_t)iclamped * 32 + kbase);
    float4 v0 = xp[0], v1 = xp[1];
    float p = v0.x * v0.x + v0.y * v0.y + v0.z * v0.z + v0.w * v0.w
            + v1.x * v1.x + v1.y * v1.y + v1.z * v1.z + v1.w * v1.w;
    p += __shfl_xor(p, 16, 64);
    p += __shfl_xor(p, 32, 64);          // |x_row|^2 for row m, all quads
    if (quad == 0) ai_lds[wave][m] = -0.5f * LOG2E * p;

    f16x8 ahi, alo;
    {
        float vv[8] = {v0.x, v0.y, v0.z, v0.w, v1.x, v1.y, v1.z, v1.w};
#pragma unroll
        for (int t = 0; t < 8; ++t) {
            float sv = vv[t] * LOG2E;
            _Float16 h = (_Float16)sv;
            ahi[t] = h;
            alo[t] = (_Float16)(sv - (float)h);
        }
    }
    __syncthreads();
    float air[4];
#pragma unroll
    for (int r = 0; r < 4; ++r) air[r] = ai_lds[wave][quad * 4 + r];

    const int jt0 = blockIdx.y * jt_per;
    const int jt1 = min(JT, jt0 + jt_per);

    float outacc[4] = {0.0f, 0.0f, 0.0f, 0.0f};
#pragma unroll 2
    for (int jt = jt0; jt < jt1; ++jt) {
        const size_t boff = (size_t)jt * 16 * 32 + (size_t)m * 32 + kbase;
        f16x8 bhi = *(const f16x8*)(chi + boff);
        f16x8 blo = *(const f16x8*)(clo + boff);
        f32x4 acc = {0.0f, 0.0f, 0.0f, 0.0f};
        acc = __builtin_amdgcn_mfma_f32_16x16x32_f16(ahi, bhi, acc, 0, 0, 0);
        acc = __builtin_amdgcn_mfma_f32_16x16x32_f16(alo, bhi, acc, 0, 0, 0);
        acc = __builtin_amdgcn_mfma_f32_16x16x32_f16(ahi, blo, acc, 0, 0, 0);
        const float2 s2 = sb[jt * 16 + m];      // col terms: s_j, beta_j
#pragma unroll
        for (int r = 0; r < 4; ++r) {
            float e = __builtin_amdgcn_exp2f(acc[r] + air[r] + s2.x);
            outacc[r] = fmaf(s2.y, e, outacc[r]);
        }
    }

    // reduce over the 16 cols (lanes differing in bits 0..3)
#pragma unroll
    for (int r = 0; r < 4; ++r) {
        float v = outacc[r];
        v += __shfl_xor(v, 1, 64);
        v += __shfl_xor(v, 2, 64);
        v += __shfl_xor(v, 4, 64);
        v += __shfl_xor(v, 8, 64);
        outacc[r] = v;
    }
    if (m == 0) {
#pragma unroll
        for (int r = 0; r < 4; ++r) {
            int row = itile * 16 + quad * 4 + r;
            if (row < N) atomicAdd(out + row, outacc[r]);
        }
    }
}

// ---------------- fallback (round-1 correct kernel) if ws too small ----------------
#define CHUNK_MAX 512
__global__ __launch_bounds__(64, 4) void krr_partial_kernel(
    const float* __restrict__ x, const float* __restrict__ c,
    const float* __restrict__ beta, float* __restrict__ out,
    int N, int M, int chunk)
{
    __shared__ float2 sw[CHUNK_MAX];
    const int lane = threadIdx.x;
    const int j0 = blockIdx.y * chunk;
    const int j1 = min(M, j0 + chunk);
    for (int j = j0 + lane; j < j1; j += 64) {
        const float4* cr = (const float4*)(c + (size_t)j * 32);
        float s = 0.0f;
#pragma unroll
        for (int q = 0; q < 8; ++q) {
            float4 v = cr[q];
            s = fmaf(v.x, v.x, s); s = fmaf(v.y, v.y, s);
            s = fmaf(v.z, v.z, s); s = fmaf(v.w, v.w, s);
        }
        sw[j - j0] = make_float2(-0.5f * LOG2E * s, beta[j]);
    }
    __syncthreads();
    const int i = blockIdx.x * 64 + lane;
    const bool valid = (i < N);
    const float4* xrow = (const float4*)(x + (size_t)(valid ? i : 0) * 32);
    float xr[32]; float xsq = 0.0f;
#pragma unroll
    for (int q = 0; q < 8; ++q) {
        float4 v = xrow[q];
        xsq = fmaf(v.x, v.x, xsq); xsq = fmaf(v.y, v.y, xsq);
        xsq = fmaf(v.z, v.z, xsq); xsq = fmaf(v.w, v.w, xsq);
        xr[4*q+0] = v.x * LOG2E; xr[4*q+1] = v.y * LOG2E;
        xr[4*q+2] = v.z * LOG2E; xr[4*q+3] = v.w * LOG2E;
    }
    const float ai = -0.5f * LOG2E * xsq;
    float acc = 0.0f;
#pragma unroll 2
    for (int j = j0; j < j1; ++j) {
        const float4* cr = (const float4*)(c + (size_t)j * 32);
        const float2 s2 = sw[j - j0];
        float d = ai + s2.x;
#pragma unroll
        for (int q = 0; q < 8; ++q) {
            float4 v = cr[q];
            d = fmaf(xr[4*q+0], v.x, d); d = fmaf(xr[4*q+1], v.y, d);
            d = fmaf(xr[4*q+2], v.z, d); d = fmaf(xr[4*q+3], v.w, d);
        }
        acc = fmaf(s2.y, __builtin_amdgcn_exp2f(d), acc);
    }
    if (valid) atomicAdd(out + i, acc);
}

extern "C" void kernel_launch(void* const* d_in, const int* in_sizes, int n_in,
                              void* d_out, int out_size, void* d_ws, size_t ws_size,
                              hipStream_t stream) {
    const float* x    = (const float*)d_in[0];   // (N, 32)
    const float* c    = (const float*)d_in[1];   // (M, 32)
    const float* beta = (const float*)d_in[2];   // (M,)
    float* out = (float*)d_out;                  // (N,)

    const int N = out_size;        // 40000
    const int M = in_sizes[2];     // 4000
    const int M16 = ((M + 15) / 16) * 16;
    const int JT = M16 / 16;

    // ws layout: chi (M16*32 halves) | clo (M16*32 halves) | sb (M16 float2)
    const size_t need = (size_t)M16 * 32 * 2 * 2 + (size_t)M16 * 8;

    zero_out_kernel<<<dim3((N + 255) / 256), dim3(256), 0, stream>>>(out, N);

    if (ws_size >= need) {
        _Float16* chi = (_Float16*)d_ws;
        _Float16* clo = chi + (size_t)M16 * 32;
        float2*   sb  = (float2*)(clo + (size_t)M16 * 32);

        prep_c_kernel<<<dim3((M16 + 255) / 256), dim3(256), 0, stream>>>(
            c, beta, chi, clo, sb, M, M16);

        const int itiles = (N + 15) / 16;            // 2500
        const int bx = (itiles + 3) / 4;             // 625 (4 waves/block)
        const int jsplit = 4;
        const int jt_per = (JT + jsplit - 1) / jsplit;
        dim3 grid(bx, jsplit);
        krr_mfma_kernel<<<grid, dim3(256), 0, stream>>>(
            x, chi, clo, sb, out, N, JT, jt_per);
    } else {
        // fallback: pure-VALU path (correct, slower)
        int jc = (M + CHUNK_MAX - 1) / CHUNK_MAX;
        if (jc < 8) jc = 8;
        int chunk = (M + jc - 1) / jc;
        dim3 grid((N + 63) / 64, jc);
        krr_partial_kernel<<<grid, dim3(64), 0, stream>>>(x, c, beta, out, N, M, chunk);
    }

    softplus_kernel<<<dim3((N + 255) / 256), dim3(256), 0, stream>>>(out, N);
}